// Round 2
// 412.854 us; speedup vs baseline: 1.1878x; 1.1878x over previous
//
#include <hip/hip_runtime.h>

typedef __bf16 bf16;
typedef __bf16 bf16x8 __attribute__((ext_vector_type(8)));
typedef float f32x4 __attribute__((ext_vector_type(4)));

#define N_ROWS 65536

// ---- packed (PRE-SWIZZLED, k-slice-contiguous) weight layout in d_ws ----
// Each k-slice is contiguous: for row r, word w(0..31): value = W[r][s*32 + ((w>>3)^swz4(r))*8 + (w&7)]
// so a LINEAR copy of the slice into LDS reproduces the exact layout the
// MFMA B-fragment reads (buf + row*32 + qs8) expect.
// W1 : 24 slices x 13312 B (208 rows)   | W12: 7 x 7168 B (112 rows)
// W13:  4 slices x  7168 B (112 rows)   | W2 : 4g x 4 x 8192 B (128 rows)
#define W1_E   159744
#define W12_E  25088
#define W13_E  14336
#define W2_E   65536
#define WP_TOTAL (W1_E + W12_E + W13_E + W2_E)        // 264704 elems
#define W12_OFF_B 319488
#define W13_OFF_B 369664
#define W2_OFF_B  398336
#define BP_OFF_BYTES (WP_TOTAL * 2)                   // 529408
#define BP_FLOATS 944
#define ACC_OFF_BYTES (BP_OFF_BYTES + BP_FLOATS * 4)  // 533184 (16B aligned)
#define NCOPY 16                                      // spread colsum atomics 16x
#define ACC_FLOATS (NCOPY * 256 + 3)
#define P0_IDX (NCOPY * 256)
#define S_IDX  (NCOPY * 256 + 1)
#define P3_IDX (NCOPY * 256 + 2)

__device__ inline int swz4(int r) { return (r ^ (r >> 2)) & 3; }

__global__ void pack_kernel(const float* __restrict__ W1, const float* __restrict__ b1,
                            const float* __restrict__ W12, const float* __restrict__ b12,
                            const float* __restrict__ W13, const float* __restrict__ b13,
                            const float* __restrict__ W2, const float* __restrict__ b2,
                            bf16* __restrict__ wp, float* __restrict__ bp) {
  int i = blockIdx.x * 256 + threadIdx.x;
  if (i < WP_TOTAL) {
    float v = 0.0f;
    if (i < W1_E) {
      int s = i / 6656, b = i - s * 6656;
      int r = b >> 5, w = b & 31;
      int k = s * 32 + (((w >> 3) ^ swz4(r)) << 3) + (w & 7);
      if (r < 200) v = W1[r * 768 + k];
    } else if (i < W1_E + W12_E) {
      int j = i - W1_E;
      int s = j / 3584, b = j - s * 3584;
      int r = b >> 5, w = b & 31;
      int k = s * 32 + (((w >> 3) ^ swz4(r)) << 3) + (w & 7);
      if (r < 100 && k < 200) v = W12[r * 200 + k];
    } else if (i < W1_E + W12_E + W13_E) {
      int j = i - (W1_E + W12_E);
      int s = j / 3584, b = j - s * 3584;
      int r = b >> 5, w = b & 31;
      int k = s * 32 + (((w >> 3) ^ swz4(r)) << 3) + (w & 7);
      if (r < 100 && k < 100) v = W13[r * 100 + k];
    } else {
      int j = i - (W1_E + W12_E + W13_E);
      int g = j >> 14, rest = j & 16383;
      int s = rest >> 12, b = rest & 4095;
      int r = b >> 5, w = b & 31;
      int o = g * 128 + r;
      int k = s * 32 + (((w >> 3) ^ swz4(r)) << 3) + (w & 7);
      if (k < 100) v = W2[o * 100 + k];
    }
    wp[i] = (bf16)v;
  } else {
    int j = i - WP_TOTAL;
    if (j < BP_FLOATS) {
      float v = 0.0f;
      if (j < 208)      { if (j < 200) v = b1[j]; }
      else if (j < 320) { int o = j - 208; if (o < 100) v = b12[o]; }
      else if (j < 432) { int o = j - 320; if (o < 100) v = b13[o]; }
      else              { v = b2[j - 432]; }
      bp[j] = v;
    }
  }
}

#define MFMA(a, b, c) __builtin_amdgcn_mfma_f32_16x16x32_bf16((a), (b), (c), 0, 0, 0)

// Direct global->LDS staging of one pre-swizzled k-slice. 4 waves cover the
// slice in 1KB chunks (wave-uniform LDS base + lane*16 — linear dest, which is
// exactly the packed layout). No VGPR roundtrip, no ds_write.
template<int BYTES>
__device__ inline void stage(const char* __restrict__ src, bf16* __restrict__ dstw, int tid) {
  char* dst = (char*)dstw;
  const int off0 = (tid >> 6) * 1024 + (tid & 63) * 16;
  constexpr int NCH = (BYTES + 4095) / 4096;
#pragma unroll
  for (int j = 0; j < NCH; j++) {
    const int off = j * 4096 + off0;
    if ((BYTES & 4095) == 0 || off < BYTES)   // wave-uniform (BYTES multiple of 1024)
      __builtin_amdgcn_global_load_lds(
          (const __attribute__((address_space(1))) void*)(src + off),
          (__attribute__((address_space(3))) void*)(dst + off),
          16, 0, 0);
  }
}

// Block = 256 threads = 4 waves; each wave runs 16 rows through all 4 layers.
// Weight k-slices double-buffered in LDS via global_load_lds; one barrier per
// k-step. Layer-1 A operands batched 8 k-steps ahead into registers (one
// exposed HBM latency per 8 steps instead of per step).
__global__ __launch_bounds__(256, 2) void mlp_main(
    const float* __restrict__ input, const float* __restrict__ h,
    const bf16* __restrict__ wp, const float* __restrict__ bp,
    float* __restrict__ out, float* __restrict__ p0_accum) {
  __shared__ __align__(16) bf16 acts[4][3712];   // x1 16x232 | x2/x3 16x136 overlay
  __shared__ __align__(16) bf16 wbuf[2][6656];   // 2 x 13312 B slices
  __shared__ float p0red[4];

  const int tid = threadIdx.x;
  const int lane = tid & 63;
  const int wave = tid >> 6;
  const int c16 = lane & 15;
  const int quad = lane >> 4;
  const int m0 = blockIdx.x * 64 + wave * 16;
  const int qs8 = (quad ^ swz4(c16)) * 8;

  const char* wpb = (const char*)wp;
  const float* b1p  = bp;
  const float* b12p = bp + 208;
  const float* b13p = bp + 320;
  const float* b2p  = bp + 432;

  bf16* actw = &acts[wave][0];

  // ---------------- Layer 1: (16x768) @ W1^T -> 16x208 ----------------
  f32x4 acc1[13];
#pragma unroll
  for (int t = 0; t < 13; t++) acc1[t] = (f32x4){0.f, 0.f, 0.f, 0.f};

  stage<13312>(wpb, wbuf[0], tid);
  __syncthreads();

  const float* arow = input + (size_t)(m0 + c16) * 512 + quad * 8;
  const float* hrow = h + (size_t)(m0 + c16) * 256 + quad * 8;
  f32x4 abuf[16];
  for (int kb = 0; kb < 3; kb++) {
#pragma unroll
    for (int b = 0; b < 8; b++) {                 // batch 8 steps of A-loads
      const int kk = kb * 8 + b;
      const float* p = (kk < 16) ? (arow + kk * 32) : (hrow + (kk - 16) * 32);
      abuf[b * 2]     = *(const f32x4*)p;
      abuf[b * 2 + 1] = *(const f32x4*)(p + 4);
    }
#pragma unroll
    for (int b = 0; b < 8; b++) {
      const int ks = kb * 8 + b;
      if (ks + 1 < 24) stage<13312>(wpb + (ks + 1) * 13312, wbuf[(b + 1) & 1], tid);
      bf16x8 a;
#pragma unroll
      for (int q = 0; q < 4; q++) { a[q] = (bf16)abuf[b * 2][q]; a[4 + q] = (bf16)abuf[b * 2 + 1][q]; }
      const bf16* buf = wbuf[b & 1];
#pragma unroll
      for (int t = 0; t < 13; t++) {
        bf16x8 bb = *(const bf16x8*)(buf + (t * 16 + c16) * 32 + qs8);
        acc1[t] = MFMA(a, bb, acc1[t]);
      }
      __syncthreads();
    }
  }
#pragma unroll
  for (int t = 0; t < 13; t++) {
    const float bias = b1p[t * 16 + c16];
#pragma unroll
    for (int r = 0; r < 4; r++)
      actw[(quad * 4 + r) * 232 + t * 16 + c16] = (bf16)fmaxf(acc1[t][r] + bias, 0.0f);
  }
  for (int idx = lane; idx < 256; idx += 64)
    actw[(idx >> 4) * 232 + 208 + (idx & 15)] = (bf16)0.0f;

  // ---------------- Layer 2: (16x224) @ W12^T -> 16x112 ----------------
  f32x4 acc2[7];
#pragma unroll
  for (int t = 0; t < 7; t++) acc2[t] = (f32x4){0.f, 0.f, 0.f, 0.f};

  stage<7168>(wpb + W12_OFF_B, wbuf[0], tid);
  __syncthreads();
#pragma unroll
  for (int ks = 0; ks < 7; ks++) {
    if (ks + 1 < 7) stage<7168>(wpb + W12_OFF_B + (ks + 1) * 7168, wbuf[(ks + 1) & 1], tid);
    bf16x8 a = *(const bf16x8*)(actw + c16 * 232 + ks * 32 + quad * 8);
    const bf16* buf = wbuf[ks & 1];
#pragma unroll
    for (int t = 0; t < 7; t++) {
      bf16x8 bb = *(const bf16x8*)(buf + (t * 16 + c16) * 32 + qs8);
      acc2[t] = MFMA(a, bb, acc2[t]);
    }
    __syncthreads();
  }
#pragma unroll
  for (int t = 0; t < 7; t++) {
    const float bias = b12p[t * 16 + c16];
#pragma unroll
    for (int r = 0; r < 4; r++)
      actw[(quad * 4 + r) * 136 + t * 16 + c16] = (bf16)fmaxf(acc2[t][r] + bias, 0.0f);
  }
  for (int idx = lane; idx < 256; idx += 64)
    actw[(idx >> 4) * 136 + 112 + (idx & 15)] = (bf16)0.0f;

  // ---------------- Layer 3: (16x128) @ W13^T -> 16x112 ----------------
  f32x4 acc3[7];
#pragma unroll
  for (int t = 0; t < 7; t++) acc3[t] = (f32x4){0.f, 0.f, 0.f, 0.f};

  stage<7168>(wpb + W13_OFF_B, wbuf[0], tid);
  __syncthreads();
#pragma unroll
  for (int ks = 0; ks < 4; ks++) {
    if (ks + 1 < 4) stage<7168>(wpb + W13_OFF_B + (ks + 1) * 7168, wbuf[(ks + 1) & 1], tid);
    bf16x8 a = *(const bf16x8*)(actw + c16 * 136 + ks * 32 + quad * 8);
    const bf16* buf = wbuf[ks & 1];
#pragma unroll
    for (int t = 0; t < 7; t++) {
      bf16x8 bb = *(const bf16x8*)(buf + (t * 16 + c16) * 32 + qs8);
      acc3[t] = MFMA(a, bb, acc3[t]);
    }
    __syncthreads();
  }
#pragma unroll
  for (int t = 0; t < 7; t++) {
    const float bias = b13p[t * 16 + c16];
#pragma unroll
    for (int r = 0; r < 4; r++)
      actw[(quad * 4 + r) * 136 + t * 16 + c16] = (bf16)fmaxf(acc3[t][r] + bias, 0.0f);
  }
  for (int idx = lane; idx < 256; idx += 64)
    actw[(idx >> 4) * 136 + 112 + (idx & 15)] = (bf16)0.0f;

  // ---------------- Layer 4: (16x128) @ W2^T -> 16x512 (+ part0) ----------------
  float p0local = 0.0f;
  for (int g = 0; g < 4; g++) {
    f32x4 acc4[8];
#pragma unroll
    for (int t = 0; t < 8; t++) acc4[t] = (f32x4){0.f, 0.f, 0.f, 0.f};

    const char* Wg = wpb + W2_OFF_B + g * 32768;
    stage<8192>(Wg, wbuf[0], tid);
    __syncthreads();
#pragma unroll
    for (int ks = 0; ks < 4; ks++) {
      if (ks + 1 < 4) stage<8192>(Wg + (ks + 1) * 8192, wbuf[(ks + 1) & 1], tid);
      bf16x8 a = *(const bf16x8*)(actw + c16 * 136 + ks * 32 + quad * 8);
      const bf16* buf = wbuf[ks & 1];
#pragma unroll
      for (int t = 0; t < 8; t++) {
        bf16x8 bb = *(const bf16x8*)(buf + (t * 16 + c16) * 32 + qs8);
        acc4[t] = MFMA(a, bb, acc4[t]);
      }
      __syncthreads();
    }
#pragma unroll
    for (int t = 0; t < 8; t++) {
      const int o = g * 128 + t * 16 + c16;
      const float bias = b2p[o];
#pragma unroll
      for (int r = 0; r < 4; r++) {
        const int grow = m0 + quad * 4 + r;
        float v = acc4[t][r] + bias;
        out[(size_t)grow * 512 + o] = v;
        if (grow < N_ROWS - 1) {
          float d = v - input[(size_t)(grow + 1) * 512 + o];
          p0local += d * d;
        }
      }
    }
  }
#pragma unroll
  for (int off = 32; off > 0; off >>= 1) p0local += __shfl_down(p0local, off);
  if (lane == 0) p0red[wave] = p0local;
  __syncthreads();
  if (tid == 0) atomicAdd(p0_accum, p0red[0] + p0red[1] + p0red[2] + p0red[3]);
}

// mu / S / part3 over h. 256 blocks x 256 rows; thread (c=t&63, rg=t>>6)
// covers cols 4c..4c+3, rows start..start+63. Colsum atomics spread over
// NCOPY=16 accumulator copies to kill same-line atomic serialization.
__global__ __launch_bounds__(256) void reduce_h(const float* __restrict__ h, float* __restrict__ acc) {
  __shared__ f32x4 cbuf[256];
  __shared__ float redS[256];
  __shared__ float redP[256];
  const int t = threadIdx.x;
  const int c = t & 63;
  const int rg = t >> 6;
  const int start = blockIdx.x * 256 + rg * 64;

  const float* base = h + (size_t)start * 256 + c * 4;
  f32x4 prev = *(const f32x4*)base;
  f32x4 csum = prev;
  f32x4 s2v = prev * prev;
  f32x4 p3v = (f32x4){0.f, 0.f, 0.f, 0.f};
#pragma unroll 8
  for (int r = 1; r < 64; r++) {
    f32x4 v = *(const f32x4*)(base + (size_t)r * 256);
    csum += v;
    s2v += v * v;
    f32x4 d = v - prev;
#pragma unroll
    for (int i = 0; i < 4; i++) p3v[i] += __builtin_fabsf(d[i]);
    prev = v;
  }
  if (start + 64 < N_ROWS) {
    f32x4 v = *(const f32x4*)(base + (size_t)64 * 256);
    f32x4 d = v - prev;
#pragma unroll
    for (int i = 0; i < 4; i++) p3v[i] += __builtin_fabsf(d[i]);
  }
  cbuf[t] = csum;
  redS[t] = s2v[0] + s2v[1] + s2v[2] + s2v[3];
  redP[t] = p3v[0] + p3v[1] + p3v[2] + p3v[3];
  __syncthreads();
  if (rg == 0) {
    f32x4 s = cbuf[c] + cbuf[c + 64] + cbuf[c + 128] + cbuf[c + 192];
    float* dst = acc + (blockIdx.x & (NCOPY - 1)) * 256 + 4 * c;
    atomicAdd(dst + 0, s[0]);
    atomicAdd(dst + 1, s[1]);
    atomicAdd(dst + 2, s[2]);
    atomicAdd(dst + 3, s[3]);
  }
  for (int st = 128; st > 0; st >>= 1) {
    if (t < st) { redS[t] += redS[t + st]; redP[t] += redP[t + st]; }
    __syncthreads();
  }
  if (t == 0) {
    atomicAdd(&acc[S_IDX], redS[0]);
    atomicAdd(&acc[P3_IDX], redP[0]);
  }
}

__global__ void finalize(const float* __restrict__ acc, float* __restrict__ out) {
  __shared__ float red[256];
  const int t = threadIdx.x;
  float s = 0.0f;
#pragma unroll
  for (int j = 0; j < NCOPY; j++) s += acc[j * 256 + t];
  red[t] = fabsf(s);
  __syncthreads();
  for (int st = 128; st > 0; st >>= 1) {
    if (t < st) red[t] += red[t + st];
    __syncthreads();
  }
  if (t == 0) {
    out[(size_t)N_ROWS * 512 + 0] = sqrtf(acc[P0_IDX]) / 65535.0f;
    out[(size_t)N_ROWS * 512 + 1] = red[0] / 65536.0f / 256.0f;
    out[(size_t)N_ROWS * 512 + 2] = fabsf(acc[S_IDX] / (65536.0f * 256.0f) - 1.0f);
    out[(size_t)N_ROWS * 512 + 3] = acc[P3_IDX] / (65535.0f * 256.0f);
  }
}

extern "C" void kernel_launch(void* const* d_in, const int* in_sizes, int n_in,
                              void* d_out, int out_size, void* d_ws, size_t ws_size,
                              hipStream_t stream) {
  const float* input = (const float*)d_in[0];
  const float* h   = (const float*)d_in[1];
  const float* W1  = (const float*)d_in[2];
  const float* b1  = (const float*)d_in[3];
  const float* W12 = (const float*)d_in[4];
  const float* b12 = (const float*)d_in[5];
  const float* W13 = (const float*)d_in[6];
  const float* b13 = (const float*)d_in[7];
  const float* W2  = (const float*)d_in[8];
  const float* b2  = (const float*)d_in[9];
  float* out = (float*)d_out;

  bf16* wp = (bf16*)d_ws;
  float* bp = (float*)((char*)d_ws + BP_OFF_BYTES);
  float* acc = (float*)((char*)d_ws + ACC_OFF_BYTES);

  hipMemsetAsync(acc, 0, ACC_FLOATS * sizeof(float), stream);
  pack_kernel<<<(WP_TOTAL + BP_FLOATS + 255) / 256, 256, 0, stream>>>(
      W1, b1, W12, b12, W13, b13, W2, b2, wp, bp);
  mlp_main<<<N_ROWS / 64, 256, 0, stream>>>(input, h, wp, bp, out, acc + P0_IDX);
  reduce_h<<<N_ROWS / 256, 256, 0, stream>>>(h, acc);
  finalize<<<1, 256, 0, stream>>>(acc, out);
}